// Round 7
// baseline (321.753 us; speedup 1.0000x reference)
//
#include <hip/hip_runtime.h>
#include <stdint.h>

// Problem constants (B=16, T=1024, F=512, H=4, dk=128, kernel=11, pad 5/5)
#define SCALE_Q 0.08838834764831845f   // 1/sqrt(128)
#define LOG2E 1.4426950408889634f
#define NEGBIG -1e30f

typedef __attribute__((ext_vector_type(4))) float f32x4;
typedef __attribute__((ext_vector_type(16))) float f32x16;
typedef __attribute__((ext_vector_type(8))) short s16x8;
typedef __attribute__((ext_vector_type(4))) unsigned u32x4;

static __device__ __forceinline__ unsigned short f2bf(float f) {
  unsigned int u = __builtin_bit_cast(unsigned int, f);
  u += 0x7FFFu + ((u >> 16) & 1u);           // round-to-nearest-even
  return (unsigned short)(u >> 16);
}
static __device__ __forceinline__ float bf2f(unsigned short b) {
  unsigned int u = ((unsigned int)b) << 16;
  return __builtin_bit_cast(float, u);
}

static __device__ __forceinline__ unsigned cvt_pk_bf16(float lo, float hi) {
  unsigned r;
  asm("v_cvt_pk_bf16_f32 %0, %1, %2" : "=v"(r) : "v"(lo), "v"(hi));
  return r;
}

static __device__ __forceinline__ float xchg_max(float x) {
  float a = x, b = x;
  asm("v_permlane32_swap_b32 %0, %1" : "+v"(a), "+v"(b));
  return fmaxf(a, b);
}
static __device__ __forceinline__ float xchg_sum(float x) {
  float a = x, b = x;
  asm("v_permlane32_swap_b32 %0, %1" : "+v"(a), "+v"(b));
  return a + b;
}

static __device__ __forceinline__ float vmax16(const f32x16& v) {
  float a = fmaxf(fmaxf(fmaxf(v[0], v[1]), fmaxf(v[2], v[3])),
                  fmaxf(fmaxf(v[4], v[5]), fmaxf(v[6], v[7])));
  float b = fmaxf(fmaxf(fmaxf(v[8], v[9]), fmaxf(v[10], v[11])),
                  fmaxf(fmaxf(v[12], v[13]), fmaxf(v[14], v[15])));
  return fmaxf(a, b);
}

// async global->LDS, 16B per lane. LDS dest must be wave-uniform base (+lane*16 implicit).
static __device__ __forceinline__ void gload16(const void* g, void* l) {
  __builtin_amdgcn_global_load_lds(
      (const __attribute__((address_space(1))) void*)g,
      (__attribute__((address_space(3))) void*)l, 16, 0, 0);
}

// ---------------------------------------------------------------- prep (fused convert + transposes)
__global__ void k_prep(const float* __restrict__ x, unsigned short* __restrict__ xb,
                       const float* __restrict__ w_qkv, unsigned short* __restrict__ wtq,
                       const float* __restrict__ w_out, unsigned short* __restrict__ wto) {
  int bid = blockIdx.x;
  int tid = threadIdx.x;
  if (bid < 4096) {
    int i = (bid * 256 + tid) * 8;
    const float4* p = reinterpret_cast<const float4*>(x + i);
    float4 a = p[0], b = p[1];
    s16x8 o;
    o[0] = f2bf(a.x); o[1] = f2bf(a.y); o[2] = f2bf(a.z); o[3] = f2bf(a.w);
    o[4] = f2bf(b.x); o[5] = f2bf(b.y); o[6] = f2bf(b.z); o[7] = f2bf(b.w);
    *reinterpret_cast<s16x8*>(xb + i) = o;
  } else if (bid < 4096 + 384) {
    int gid = (bid - 4096) * 256 + tid;
    int n = gid >> 6, k0 = (gid & 63) * 8;
    s16x8 o;
#pragma unroll
    for (int j = 0; j < 8; ++j) o[j] = f2bf(w_qkv[(size_t)(k0 + j) * 1536 + n]);
    *reinterpret_cast<s16x8*>(wtq + (size_t)n * 512 + k0) = o;
  } else {
    int gid = (bid - 4480) * 256 + tid;
    int n = gid >> 6, k0 = (gid & 63) * 8;
    s16x8 o;
#pragma unroll
    for (int j = 0; j < 8; ++j) o[j] = f2bf(w_out[(size_t)(k0 + j) * 512 + n]);
    *reinterpret_cast<s16x8*>(wto + (size_t)n * 512 + k0) = o;
  }
}

// ---------------------------------------------------------------- GEMM core
// A [M][512] bf16, Bt [N][512] bf16. 128x128 tile, BK=64, 4 waves (2x2), 16x16x32 MFMA.
// Double-buffered global_load_lds, prefetch-under-compute, rb-major L2 mapping.
// MODE 0: qkv epilogue (scatter q,k,v_bf16,vT) + masked-row tile skip.
// MODE 1: out epilogue (+bias + FUSED FSMN depthwise conv + residual -> fp32).
template <int MODE>
__launch_bounds__(256, 2)
__global__ void k_gemm(const unsigned short* __restrict__ A,
                       const unsigned short* __restrict__ Bt,
                       const float* __restrict__ bias,
                       const float* __restrict__ mask,
                       const float* __restrict__ wf,      // w_fsmn (MODE 1)
                       const unsigned short* __restrict__ vsrc, // v bf16 [b,t,d] (MODE 1)
                       unsigned short* __restrict__ qs, unsigned short* __restrict__ kbuf,
                       unsigned short* __restrict__ vbf, unsigned short* __restrict__ vt,
                       float* __restrict__ outp,
                       int tiles_n, int cpx) {
  __shared__ unsigned short smem[32768];     // 64KB: 2 bufs x (A 16KB | B 16KB)
  int bid0 = blockIdx.x;
  int bid = (bid0 & 7) * cpx + (bid0 >> 3);  // XCD swizzle (grid % 8 == 0)
  int rb = bid / tiles_n, cb = bid % tiles_n;
  int tid = threadIdx.x;
  int w = tid >> 6, lane = tid & 63;
  int g = lane >> 4, ln = lane & 15;
  int wr = w >> 1, wc = w & 1;

  if constexpr (MODE == 0) {
    if (cb >= 4) {
      int b = (rb * 128) >> 10, t0 = (rb * 128) & 1023;
      const float* mb = mask + b * 1024 + t0;
      float a0 = mb[lane * 2], a1 = mb[lane * 2 + 1];
      if (__ballot(a0 != 0.f || a1 != 0.f) == 0ull) return;
    }
  }

  int sr = lane >> 3;        // row within wave chunk (8 rows/wave/round)
  int sc = lane & 7;         // 16B-granule slot (8 per 128B row)

  auto stage = [&](int kb0, int bsel) {
    unsigned short* al = smem + bsel * 16384;
    unsigned short* bl = al + 8192;
#pragma unroll
    for (int it = 0; it < 4; ++it) {
      int r0 = it * 32 + w * 8;                // wave-uniform row base
      int r = r0 + sr;
      int cg = sc ^ (r & 7);                   // pre-swizzled global granule
      gload16(A + (size_t)(rb * 128 + r) * 512 + kb0 + cg * 8, al + r0 * 64);
      gload16(Bt + (size_t)(cb * 128 + r) * 512 + kb0 + cg * 8, bl + r0 * 64);
    }
  };

  f32x4 acc[4][4] = {};

  stage(0, 0);
  __syncthreads();
  int cur = 0;
  for (int kt = 0; kt < 8; ++kt) {
    if (kt < 7) stage((kt + 1) * 64, cur ^ 1); // flies under compute
    const unsigned short* al = smem + cur * 16384;
    const unsigned short* bl = al + 8192;
#pragma unroll
    for (int kk = 0; kk < 2; ++kk) {
      s16x8 af[4], bf[4];
#pragma unroll
      for (int m = 0; m < 4; ++m) {
        int row = wr * 64 + m * 16 + ln;
        af[m] = *reinterpret_cast<const s16x8*>(al + row * 64 + (((kk * 4 + g) ^ (row & 7)) * 8));
      }
#pragma unroll
      for (int n = 0; n < 4; ++n) {
        int row = wc * 64 + n * 16 + ln;
        bf[n] = *reinterpret_cast<const s16x8*>(bl + row * 64 + (((kk * 4 + g) ^ (row & 7)) * 8));
      }
#pragma unroll
      for (int m = 0; m < 4; ++m)
#pragma unroll
        for (int n = 0; n < 4; ++n)
          acc[m][n] = __builtin_amdgcn_mfma_f32_16x16x32_bf16(af[m], bf[n], acc[m][n], 0, 0, 0);
    }
    __syncthreads();
    cur ^= 1;
  }

  int c0 = cb * 128;
  int R0 = rb * 128 + wr * 64;

  if constexpr (MODE == 0) {
#pragma unroll
    for (int m = 0; m < 4; ++m) {
#pragma unroll
      for (int n = 0; n < 4; ++n) {
        int col = c0 + wc * 64 + n * 16 + ln;
        int Rbase = R0 + m * 16 + g * 4;
        float bv = bias[col];
        int which = col >> 9;          // 0=q 1=k 2=v  (uniform per block)
        int h = (col >> 7) & 3;        // uniform per block
        int d = col & 127;
        int b = Rbase >> 10, t0 = Rbase & 1023;
        if (which == 2) {
          unsigned short pk[4];
#pragma unroll
          for (int r = 0; r < 4; ++r) {
            float v = acc[m][n][r] + bv;
            pk[r] = f2bf(v);
            vbf[(size_t)(Rbase + r) * 512 + (col - 1024)] = pk[r];
          }
          uint2 uv;
          uv.x = (unsigned)pk[0] | ((unsigned)pk[1] << 16);
          uv.y = (unsigned)pk[2] | ((unsigned)pk[3] << 16);
          *reinterpret_cast<uint2*>(vt + ((size_t)((b * 4 + h) * 128 + d)) * 1024 + t0) = uv;
        } else {
          unsigned short* dst = (which == 0) ? qs : kbuf;
          float sc2 = (which == 0) ? (SCALE_Q * LOG2E) : 1.0f;   // fold log2e for exp2 softmax
#pragma unroll
          for (int r = 0; r < 4; ++r) {
            int t = t0 + r;
            dst[((size_t)((b * 4 + h) * 1024 + t)) * 128 + d] = f2bf((acc[m][n][r] + bv) * sc2);
          }
        }
      }
    }
  } else {
    // fused FSMN epilogue
    int b = (rb * 128) >> 10, tloc0 = (rb * 128) & 1023;
    unsigned short* vh = smem;                          // 138*136 u16
    float* wl = reinterpret_cast<float*>(smem + 18816); // 128*11 f32
    for (int idx = tid; idx < 138 * 16; idx += 256) {
      int i = idx >> 4, gc = idx & 15;
      int tl = tloc0 - 5 + i;
      s16x8 v8 = {};
      if (tl >= 0 && tl < 1024) {
        if (mask[b * 1024 + tl] != 0.f)
          v8 = *reinterpret_cast<const s16x8*>(vsrc + ((size_t)b * 1024 + tl) * 512 + c0 + gc * 8);
      }
      *reinterpret_cast<s16x8*>(vh + i * 136 + gc * 8) = v8;
    }
    if (tid < 128) {
#pragma unroll
      for (int j = 0; j < 11; ++j) wl[tid * 11 + j] = wf[(c0 + tid) * 11 + j];
    }
    __syncthreads();

#pragma unroll
    for (int m = 0; m < 4; ++m) {
      int Rbase = R0 + m * 16 + g * 4;
      int lrb = Rbase - rb * 128;
      float mk[4];
#pragma unroll
      for (int r = 0; r < 4; ++r) mk[r] = mask[b * 1024 + ((Rbase + r) & 1023)];
#pragma unroll
      for (int n = 0; n < 4; ++n) {
        int lc = wc * 64 + n * 16 + ln;
        int col = c0 + lc;
        float bv = bias[col];
        float win[14];
#pragma unroll
        for (int i = 0; i < 14; ++i) win[i] = bf2f(vh[(lrb + i) * 136 + lc]);
        float wj[11];
#pragma unroll
        for (int j = 0; j < 11; ++j) wj[j] = wl[lc * 11 + j];
#pragma unroll
        for (int r = 0; r < 4; ++r) {
          float conv = win[r + 5];         // residual
#pragma unroll
          for (int j = 0; j < 11; ++j) conv += wj[j] * win[r + j];
          size_t idx = (size_t)(Rbase + r) * 512 + col;
          outp[idx] = acc[m][n][r] + bv + conv * mk[r];
        }
      }
    }
  }
}

// ---------------------------------------------------------------- flash attention (in-block KV-split)
// 512 blocks x 512 thr. 8 waves = 2 KV-groups x 4 q-waves (128 q/block).
// Group g handles active tiles [2i+g]; KVBLK=64, single-buffered 32KB/group.
// Swapped-QK^T in-reg softmax + defer-max; end-of-block flash merge via LDS.
__launch_bounds__(512, 4)
__global__ void k_attn(const unsigned short* __restrict__ qs,
                       const unsigned short* __restrict__ kbuf,
                       const unsigned short* __restrict__ vt,
                       const float* __restrict__ mask,
                       unsigned short* __restrict__ ctx) {
  __shared__ unsigned short smem[33280];   // 65KB: 2 x (K 16KB | V^T 16KB); reuse: o-share 64KB + ML 1KB; obuf 32KB

  int bid0 = blockIdx.x;
  int bid = (bid0 & 7) * 64 + (bid0 >> 3);   // XCD chunked: 8 bh per XCD
  int qc = bid & 7;                          // 8 q-chunks of 128
  int bh = bid >> 3;
  int b = bh >> 2, h = bh & 3;
  int tid = threadIdx.x;
  int w = tid >> 6, l = tid & 63;
  int kvg = w >> 2, wq = w & 3, sw = w & 3;
  int half = l >> 5, lq = l & 31;

  const unsigned short* kbase = kbuf + (size_t)bh * 1024 * 128;
  const unsigned short* vtbase = vt + (size_t)bh * 128 * 1024;
  const float* mbase = mask + b * 1024;

  // Q fragments (B-operand): lane: q = lq, dk = c*16 + half*8 + j
  s16x8 aq[8];
  {
    const unsigned short* qrow = qs + ((size_t)bh * 1024 + qc * 128 + wq * 32 + lq) * 128 + half * 8;
#pragma unroll
    for (int c = 0; c < 8; ++c)
      aq[c] = *reinterpret_cast<const s16x8*>(qrow + c * 16);
  }

  s16x8 bone = {};                        // B[k][q] = 1 at k==0
  bone[0] = (short)(half == 0 ? 0x3F80 : 0);

  f32x16 o[4] = {};                       // O^T tiles, d = dt*32 + rows
  float M = NEGBIG, L = 0.f;

  // active-KV bitmask over 16 tiles of 64 (wave-uniform)
  unsigned amask = 0;
  for (int kb = 0; kb < 16; ++kb) {
    if (__ballot(mbase[kb * 64 + l] != 0.f) != 0ull) amask |= (1u << kb);
  }

  unsigned short* mybuf = smem + kvg * 16384;

  // stage one 64-key tile with a 4-wave group (sw in 0..3)
  auto stage4 = [&](int kb) {
    unsigned short* kd = mybuf;
    unsigned short* vd = mybuf + 8192;
    int rk = l >> 4, ck = l & 15;
#pragma unroll
    for (int it = 0; it < 4; ++it) {
      int r0 = it * 16 + sw * 4;
      int r = r0 + rk;
      int cg = ck ^ (r & 15);
      gload16(kbase + (size_t)(kb * 64 + r) * 128 + cg * 8, kd + r0 * 128);
    }
    int rv = l >> 3, cv = l & 7;
#pragma unroll
    for (int it = 0; it < 4; ++it) {
      int r0 = it * 32 + sw * 8;
      int r = r0 + rv;
      int cg = cv ^ (r & 7);
      gload16(vtbase + (size_t)r * 1024 + kb * 64 + cg * 8, vd + r0 * 64);
    }
  };

  unsigned rem = amask;
  while (rem) {
    int kba = __ffs(rem) - 1; rem &= rem - 1;
    int kbb = -1;
    if (rem) { kbb = __ffs(rem) - 1; rem &= rem - 1; }
    int mykb = kvg ? kbb : kba;

    __syncthreads();                      // prior tile's readers done
    if (mykb >= 0) stage4(mykb);
    __syncthreads();                      // staged data visible

    if (mykb >= 0) {
      const unsigned short* kl = mybuf;
      const unsigned short* vl = mybuf + 8192;

      // ---- QK^T: 2 tiles of S^T[32k][32q]; bias-MFMA injects -BIG at masked k
      f32x16 s[2];
      __builtin_amdgcn_s_setprio(1);
#pragma unroll
      for (int kt = 0; kt < 2; ++kt) {
        float mv = mbase[mykb * 64 + kt * 32 + lq];
        s16x8 ba = {};
        ba[0] = (short)((half == 0 && mv == 0.f) ? (short)0xFF7F : 0);  // bf16 -3.39e38
        f32x16 z = {};
        s[kt] = __builtin_amdgcn_mfma_f32_32x32x16_bf16(ba, bone, z, 0, 0, 0);
        int row = kt * 32 + lq, rx = row & 15;
#pragma unroll
        for (int c = 0; c < 8; ++c) {
          s16x8 kf = *reinterpret_cast<const s16x8*>(kl + row * 128 + (((c * 2 + half) ^ rx) * 8));
          s[kt] = __builtin_amdgcn_mfma_f32_32x32x16_bf16(kf, aq[c], s[kt], 0, 0, 0);
        }
      }
      __builtin_amdgcn_s_setprio(0);

      // ---- online softmax with defer-max (log2 domain)
      float pmax = fmaxf(vmax16(s[0]), vmax16(s[1]));
      pmax = xchg_max(pmax);
      if (!__all(pmax <= M + 8.f)) {
        float mnew = fmaxf(M, pmax);
        float alpha = exp2f(M - mnew);
        M = mnew;
        L *= alpha;
#pragma unroll
        for (int dt = 0; dt < 4; ++dt)
#pragma unroll
          for (int i = 0; i < 16; ++i) o[dt][i] *= alpha;
      }
      float ls0 = 0.f, ls1 = 0.f, ls2 = 0.f, ls3 = 0.f;
#pragma unroll
      for (int kt = 0; kt < 2; ++kt) {
#pragma unroll
        for (int i = 0; i < 16; ++i) {
          float p = exp2f(s[kt][i] - M);
          s[kt][i] = p;
          if ((i & 3) == 0) ls0 += p; else if ((i & 3) == 1) ls1 += p;
          else if ((i & 3) == 2) ls2 += p; else ls3 += p;
        }
      }
      float ls = (ls0 + ls1) + (ls2 + ls3);
      ls = xchg_sum(ls);
      L += ls;

      // ---- pack P^T (cvt_pk + permlane32_swap) and PV
      __builtin_amdgcn_s_setprio(1);
#pragma unroll
      for (int kt = 0; kt < 2; ++kt) {
        unsigned w0 = cvt_pk_bf16(s[kt][0], s[kt][1]);
        unsigned w1 = cvt_pk_bf16(s[kt][2], s[kt][3]);
        unsigned w2 = cvt_pk_bf16(s[kt][4], s[kt][5]);
        unsigned w3 = cvt_pk_bf16(s[kt][6], s[kt][7]);
        unsigned w4 = cvt_pk_bf16(s[kt][8], s[kt][9]);
        unsigned w5 = cvt_pk_bf16(s[kt][10], s[kt][11]);
        unsigned w6 = cvt_pk_bf16(s[kt][12], s[kt][13]);
        unsigned w7 = cvt_pk_bf16(s[kt][14], s[kt][15]);
        asm("v_permlane32_swap_b32 %0, %1" : "+v"(w0), "+v"(w2));
        asm("v_permlane32_swap_b32 %0, %1" : "+v"(w1), "+v"(w3));
        asm("v_permlane32_swap_b32 %0, %1" : "+v"(w4), "+v"(w6));
        asm("v_permlane32_swap_b32 %0, %1" : "+v"(w5), "+v"(w7));
        u32x4 f0 = {w0, w1, w2, w3};
        u32x4 f1 = {w4, w5, w6, w7};
        s16x8 p0 = __builtin_bit_cast(s16x8, f0);   // k = kt*32 + 0..15
        s16x8 p1 = __builtin_bit_cast(s16x8, f1);   // k = kt*32 + 16..31
#pragma unroll
        for (int dt = 0; dt < 4; ++dt) {
          int row = dt * 32 + lq, rx = row & 7;
          s16x8 va = *reinterpret_cast<const s16x8*>(vl + row * 64 + (((kt * 4 + half) ^ rx) * 8));
          o[dt] = __builtin_amdgcn_mfma_f32_32x32x16_bf16(va, p0, o[dt], 0, 0, 0);
          s16x8 vb = *reinterpret_cast<const s16x8*>(vl + row * 64 + (((kt * 4 + 2 + half) ^ rx) * 8));
          o[dt] = __builtin_amdgcn_mfma_f32_32x32x16_bf16(vb, p1, o[dt], 0, 0, 0);
        }
      }
      __builtin_amdgcn_s_setprio(0);
    }
  }

  // ---- flash merge of the two KV-groups via LDS
  __syncthreads();                        // all compute done, smem free
  float* oshare = reinterpret_cast<float*>(smem);            // [wq][d=128][q=32]
  float* mlf = reinterpret_cast<float*>(smem) + 16384;       // [wq][q=32][2]
  if (kvg == 1) {
#pragma unroll
    for (int dt = 0; dt < 4; ++dt)
#pragma unroll
      for (int i = 0; i < 16; ++i) {
        int rowi = (i & 3) + 8 * (i >> 2) + 4 * half;
        oshare[wq * 4096 + (dt * 32 + rowi) * 32 + lq] = o[dt][i];
      }
    if (half == 0) { mlf[wq * 64 + lq * 2] = M; mlf[wq * 64 + lq * 2 + 1] = L; }
  }
  __syncthreads();
  if (kvg == 0) {
    float M1 = mlf[wq * 64 + lq * 2], L1 = mlf[wq * 64 + lq * 2 + 1];
    float mnew = fmaxf(M, M1);
    float a0 = exp2f(M - mnew), a1 = exp2f(M1 - mnew);
    L = L * a0 + L1 * a1;
#pragma unroll
    for (int dt = 0; dt < 4; ++dt)
#pragma unroll
      for (int i = 0; i < 16; ++i) {
        int rowi = (i & 3) + 8 * (i >> 2) + 4 * half;
        o[dt][i] = o[dt][i] * a0 + oshare[wq * 4096 + (dt * 32 + rowi) * 32 + lq] * a1;
      }
  }
  __syncthreads();

  // ---- epilogue: O^T -> LDS transpose -> coalesced ctx write (g0 holds merged o)
  unsigned short* obuf = smem;            // [128 q][128 d] bf16, 8B-granule XOR (row&15)
  if (kvg == 0) {
    float inv = (L > 0.f) ? 1.0f / L : 0.f;
#pragma unroll
    for (int dt = 0; dt < 4; ++dt) {
#pragma unroll
      for (int g = 0; g < 4; ++g) {
        int d0 = dt * 32 + g * 8 + half * 4;
        unsigned lo = cvt_pk_bf16(o[dt][g * 4 + 0] * inv, o[dt][g * 4 + 1] * inv);
        unsigned hi = cvt_pk_bf16(o[dt][g * 4 + 2] * inv, o[dt][g * 4 + 3] * inv);
        int row = wq * 32 + lq;
        int gr = d0 >> 2;
        uint2 uv; uv.x = lo; uv.y = hi;
        *reinterpret_cast<uint2*>(obuf + row * 128 + ((gr ^ (row & 15)) * 4)) = uv;
      }
    }
  }
  __syncthreads();
  size_t cbase = ((size_t)b * 1024 + qc * 128) * 512 + h * 128;
#pragma unroll
  for (int it = 0; it < 8; ++it) {
    int chunk = it * 512 + tid;
    int row = chunk >> 5, gr = chunk & 31;
    uint2 v = *reinterpret_cast<uint2*>(obuf + row * 128 + ((gr ^ (row & 15)) * 4));
    *reinterpret_cast<uint2*>(ctx + cbase + (size_t)row * 512 + gr * 4) = v;
  }
}

// ---------------------------------------------------------------- launch
extern "C" void kernel_launch(void* const* d_in, const int* in_sizes, int n_in,
                              void* d_out, int out_size, void* d_ws, size_t ws_size,
                              hipStream_t stream) {
  const float* x      = (const float*)d_in[0];
  const float* mask   = (const float*)d_in[1];
  const float* w_qkv  = (const float*)d_in[2];
  const float* b_qkv  = (const float*)d_in[3];
  const float* w_out  = (const float*)d_in[4];
  const float* b_out  = (const float*)d_in[5];
  const float* w_fsmn = (const float*)d_in[6];
  float* out = (float*)d_out;

  char* ws = (char*)d_ws;
  size_t off = 0;
  auto alloc = [&](size_t bytes) { void* p = ws + off; off += (bytes + 255) & ~(size_t)255; return p; };
  unsigned short* x_bf   = (unsigned short*)alloc(16384ull * 512 * 2);
  unsigned short* wT_qkv = (unsigned short*)alloc(1536ull * 512 * 2);
  unsigned short* wT_out = (unsigned short*)alloc(512ull * 512 * 2);
  unsigned short* qs     = (unsigned short*)alloc(64ull * 1024 * 128 * 2);
  unsigned short* kbuf   = (unsigned short*)alloc(64ull * 1024 * 128 * 2);
  unsigned short* vt     = (unsigned short*)alloc(64ull * 128 * 1024 * 2);
  unsigned short* vbf    = (unsigned short*)alloc(16384ull * 512 * 2);
  unsigned short* ctx    = (unsigned short*)alloc(16384ull * 512 * 2);

  k_prep<<<4608, 256, 0, stream>>>(x, x_bf, w_qkv, wT_qkv, w_out, wT_out);
  k_gemm<0><<<128 * 12, 256, 0, stream>>>(x_bf, wT_qkv, b_qkv, mask, nullptr, nullptr,
                                          qs, kbuf, vbf, vt, nullptr, 12, (128 * 12) / 8);
  k_attn<<<512, 512, 0, stream>>>(qs, kbuf, vt, mask, ctx);
  k_gemm<1><<<128 * 4, 256, 0, stream>>>(ctx, wT_out, b_out, mask, w_fsmn, vbf,
                                         nullptr, nullptr, nullptr, nullptr, out, 4, (128 * 4) / 8);
}

// Round 8
// 214.656 us; speedup vs baseline: 1.4989x; 1.4989x over previous
//
#include <hip/hip_runtime.h>
#include <stdint.h>

// Problem constants (B=16, T=1024, F=512, H=4, dk=128, kernel=11, pad 5/5)
#define SCALE_Q 0.08838834764831845f   // 1/sqrt(128)
#define LOG2E 1.4426950408889634f
#define NEGBIG -1e30f

typedef __attribute__((ext_vector_type(4))) float f32x4;
typedef __attribute__((ext_vector_type(16))) float f32x16;
typedef __attribute__((ext_vector_type(8))) short s16x8;
typedef __attribute__((ext_vector_type(4))) unsigned u32x4;

static __device__ __forceinline__ unsigned short f2bf(float f) {
  unsigned int u = __builtin_bit_cast(unsigned int, f);
  u += 0x7FFFu + ((u >> 16) & 1u);           // round-to-nearest-even
  return (unsigned short)(u >> 16);
}
static __device__ __forceinline__ float bf2f(unsigned short b) {
  unsigned int u = ((unsigned int)b) << 16;
  return __builtin_bit_cast(float, u);
}

static __device__ __forceinline__ unsigned cvt_pk_bf16(float lo, float hi) {
  unsigned r;
  asm("v_cvt_pk_bf16_f32 %0, %1, %2" : "=v"(r) : "v"(lo), "v"(hi));
  return r;
}

static __device__ __forceinline__ float xchg_max(float x) {
  float a = x, b = x;
  asm("v_permlane32_swap_b32 %0, %1" : "+v"(a), "+v"(b));
  return fmaxf(a, b);
}
static __device__ __forceinline__ float xchg_sum(float x) {
  float a = x, b = x;
  asm("v_permlane32_swap_b32 %0, %1" : "+v"(a), "+v"(b));
  return a + b;
}

static __device__ __forceinline__ float vmax16(const f32x16& v) {
  float a = fmaxf(fmaxf(fmaxf(v[0], v[1]), fmaxf(v[2], v[3])),
                  fmaxf(fmaxf(v[4], v[5]), fmaxf(v[6], v[7])));
  float b = fmaxf(fmaxf(fmaxf(v[8], v[9]), fmaxf(v[10], v[11])),
                  fmaxf(fmaxf(v[12], v[13]), fmaxf(v[14], v[15])));
  return fmaxf(a, b);
}

// async global->LDS, 16B per lane. LDS dest must be wave-uniform base (+lane*16 implicit).
static __device__ __forceinline__ void gload16(const void* g, void* l) {
  __builtin_amdgcn_global_load_lds(
      (const __attribute__((address_space(1))) void*)g,
      (__attribute__((address_space(3))) void*)l, 16, 0, 0);
}

// ---------------------------------------------------------------- prep (fused convert + transposes)
__global__ void k_prep(const float* __restrict__ x, unsigned short* __restrict__ xb,
                       const float* __restrict__ w_qkv, unsigned short* __restrict__ wtq,
                       const float* __restrict__ w_out, unsigned short* __restrict__ wto) {
  int bid = blockIdx.x;
  int tid = threadIdx.x;
  if (bid < 4096) {
    int i = (bid * 256 + tid) * 8;
    const float4* p = reinterpret_cast<const float4*>(x + i);
    float4 a = p[0], b = p[1];
    s16x8 o;
    o[0] = f2bf(a.x); o[1] = f2bf(a.y); o[2] = f2bf(a.z); o[3] = f2bf(a.w);
    o[4] = f2bf(b.x); o[5] = f2bf(b.y); o[6] = f2bf(b.z); o[7] = f2bf(b.w);
    *reinterpret_cast<s16x8*>(xb + i) = o;
  } else if (bid < 4096 + 384) {
    int gid = (bid - 4096) * 256 + tid;
    int n = gid >> 6, k0 = (gid & 63) * 8;
    s16x8 o;
#pragma unroll
    for (int j = 0; j < 8; ++j) o[j] = f2bf(w_qkv[(size_t)(k0 + j) * 1536 + n]);
    *reinterpret_cast<s16x8*>(wtq + (size_t)n * 512 + k0) = o;
  } else {
    int gid = (bid - 4480) * 256 + tid;
    int n = gid >> 6, k0 = (gid & 63) * 8;
    s16x8 o;
#pragma unroll
    for (int j = 0; j < 8; ++j) o[j] = f2bf(w_out[(size_t)(k0 + j) * 512 + n]);
    *reinterpret_cast<s16x8*>(wto + (size_t)n * 512 + k0) = o;
  }
}

// ---------------------------------------------------------------- GEMM core
// A [M][512] bf16, Bt [N][512] bf16. 128x128 tile, BK=64, 4 waves (2x2), 16x16x32 MFMA.
// Double-buffered global_load_lds, prefetch-under-compute, rb-major L2 mapping.
// MODE 0: qkv epilogue (scatter q,k,v_bf16,vT) + masked-row tile skip.
// MODE 1: out epilogue (+bias + FUSED FSMN depthwise conv + residual -> fp32).
template <int MODE>
__launch_bounds__(256, 2)
__global__ void k_gemm(const unsigned short* __restrict__ A,
                       const unsigned short* __restrict__ Bt,
                       const float* __restrict__ bias,
                       const float* __restrict__ mask,
                       const float* __restrict__ wf,      // w_fsmn (MODE 1)
                       const unsigned short* __restrict__ vsrc, // v bf16 [b,t,d] (MODE 1)
                       unsigned short* __restrict__ qs, unsigned short* __restrict__ kbuf,
                       unsigned short* __restrict__ vbf, unsigned short* __restrict__ vt,
                       float* __restrict__ outp,
                       int tiles_n, int cpx) {
  __shared__ unsigned short smem[32768];     // 64KB: 2 bufs x (A 16KB | B 16KB)
  int bid0 = blockIdx.x;
  int bid = (bid0 & 7) * cpx + (bid0 >> 3);  // XCD swizzle (grid % 8 == 0)
  int rb = bid / tiles_n, cb = bid % tiles_n;
  int tid = threadIdx.x;
  int w = tid >> 6, lane = tid & 63;
  int g = lane >> 4, ln = lane & 15;
  int wr = w >> 1, wc = w & 1;

  if constexpr (MODE == 0) {
    if (cb >= 4) {
      int b = (rb * 128) >> 10, t0 = (rb * 128) & 1023;
      const float* mb = mask + b * 1024 + t0;
      float a0 = mb[lane * 2], a1 = mb[lane * 2 + 1];
      if (__ballot(a0 != 0.f || a1 != 0.f) == 0ull) return;
    }
  }

  int sr = lane >> 3;        // row within wave chunk (8 rows/wave/round)
  int sc = lane & 7;         // 16B-granule slot (8 per 128B row)

  auto stage = [&](int kb0, int bsel) {
    unsigned short* al = smem + bsel * 16384;
    unsigned short* bl = al + 8192;
#pragma unroll
    for (int it = 0; it < 4; ++it) {
      int r0 = it * 32 + w * 8;                // wave-uniform row base
      int r = r0 + sr;
      int cg = sc ^ (r & 7);                   // pre-swizzled global granule
      gload16(A + (size_t)(rb * 128 + r) * 512 + kb0 + cg * 8, al + r0 * 64);
      gload16(Bt + (size_t)(cb * 128 + r) * 512 + kb0 + cg * 8, bl + r0 * 64);
    }
  };

  f32x4 acc[4][4] = {};

  stage(0, 0);
  __syncthreads();
  int cur = 0;
  for (int kt = 0; kt < 8; ++kt) {
    if (kt < 7) stage((kt + 1) * 64, cur ^ 1); // flies under compute
    const unsigned short* al = smem + cur * 16384;
    const unsigned short* bl = al + 8192;
#pragma unroll
    for (int kk = 0; kk < 2; ++kk) {
      s16x8 af[4], bf[4];
#pragma unroll
      for (int m = 0; m < 4; ++m) {
        int row = wr * 64 + m * 16 + ln;
        af[m] = *reinterpret_cast<const s16x8*>(al + row * 64 + (((kk * 4 + g) ^ (row & 7)) * 8));
      }
#pragma unroll
      for (int n = 0; n < 4; ++n) {
        int row = wc * 64 + n * 16 + ln;
        bf[n] = *reinterpret_cast<const s16x8*>(bl + row * 64 + (((kk * 4 + g) ^ (row & 7)) * 8));
      }
#pragma unroll
      for (int m = 0; m < 4; ++m)
#pragma unroll
        for (int n = 0; n < 4; ++n)
          acc[m][n] = __builtin_amdgcn_mfma_f32_16x16x32_bf16(af[m], bf[n], acc[m][n], 0, 0, 0);
    }
    __syncthreads();
    cur ^= 1;
  }

  int c0 = cb * 128;
  int R0 = rb * 128 + wr * 64;

  if constexpr (MODE == 0) {
#pragma unroll
    for (int m = 0; m < 4; ++m) {
#pragma unroll
      for (int n = 0; n < 4; ++n) {
        int col = c0 + wc * 64 + n * 16 + ln;
        int Rbase = R0 + m * 16 + g * 4;
        float bv = bias[col];
        int which = col >> 9;          // 0=q 1=k 2=v  (uniform per block)
        int h = (col >> 7) & 3;        // uniform per block
        int d = col & 127;
        int b = Rbase >> 10, t0 = Rbase & 1023;
        if (which == 2) {
          unsigned short pk[4];
#pragma unroll
          for (int r = 0; r < 4; ++r) {
            float v = acc[m][n][r] + bv;
            pk[r] = f2bf(v);
            vbf[(size_t)(Rbase + r) * 512 + (col - 1024)] = pk[r];
          }
          uint2 uv;
          uv.x = (unsigned)pk[0] | ((unsigned)pk[1] << 16);
          uv.y = (unsigned)pk[2] | ((unsigned)pk[3] << 16);
          *reinterpret_cast<uint2*>(vt + ((size_t)((b * 4 + h) * 128 + d)) * 1024 + t0) = uv;
        } else {
          unsigned short* dst = (which == 0) ? qs : kbuf;
          float sc2 = (which == 0) ? (SCALE_Q * LOG2E) : 1.0f;   // fold log2e for exp2 softmax
#pragma unroll
          for (int r = 0; r < 4; ++r) {
            int t = t0 + r;
            dst[((size_t)((b * 4 + h) * 1024 + t)) * 128 + d] = f2bf((acc[m][n][r] + bv) * sc2);
          }
        }
      }
    }
  } else {
    // fused FSMN epilogue
    int b = (rb * 128) >> 10, tloc0 = (rb * 128) & 1023;
    unsigned short* vh = smem;                          // 138*136 u16
    float* wl = reinterpret_cast<float*>(smem + 18816); // 128*11 f32
    for (int idx = tid; idx < 138 * 16; idx += 256) {
      int i = idx >> 4, gc = idx & 15;
      int tl = tloc0 - 5 + i;
      s16x8 v8 = {};
      if (tl >= 0 && tl < 1024) {
        if (mask[b * 1024 + tl] != 0.f)
          v8 = *reinterpret_cast<const s16x8*>(vsrc + ((size_t)b * 1024 + tl) * 512 + c0 + gc * 8);
      }
      *reinterpret_cast<s16x8*>(vh + i * 136 + gc * 8) = v8;
    }
    if (tid < 128) {
#pragma unroll
      for (int j = 0; j < 11; ++j) wl[tid * 11 + j] = wf[(c0 + tid) * 11 + j];
    }
    __syncthreads();

#pragma unroll
    for (int m = 0; m < 4; ++m) {
      int Rbase = R0 + m * 16 + g * 4;
      int lrb = Rbase - rb * 128;
      float mk[4];
#pragma unroll
      for (int r = 0; r < 4; ++r) mk[r] = mask[b * 1024 + ((Rbase + r) & 1023)];
#pragma unroll
      for (int n = 0; n < 4; ++n) {
        int lc = wc * 64 + n * 16 + ln;
        int col = c0 + lc;
        float bv = bias[col];
        float win[14];
#pragma unroll
        for (int i = 0; i < 14; ++i) win[i] = bf2f(vh[(lrb + i) * 136 + lc]);
        float wj[11];
#pragma unroll
        for (int j = 0; j < 11; ++j) wj[j] = wl[lc * 11 + j];
#pragma unroll
        for (int r = 0; r < 4; ++r) {
          float conv = win[r + 5];         // residual
#pragma unroll
          for (int j = 0; j < 11; ++j) conv += wj[j] * win[r + j];
          size_t idx = (size_t)(Rbase + r) * 512 + col;
          outp[idx] = acc[m][n][r] + bv + conv * mk[r];
        }
      }
    }
  }
}

// ---------------------------------------------------------------- flash attention (in-block KV-split)
// 512 blocks x 512 thr. 8 waves = 2 KV-groups x 4 q-waves (128 q/block).
// Group g handles active tiles [2i+g]; KVBLK=64, single-buffered 32KB/group.
// K tile: [64 k][128 d] 256B rows, XOR (r&15). V tile: packed dual-d [64 rows][128],
// row r = {d=r: k0..63 | d=r+64: k0..63}, XOR (r&15) — both are the verified
// conflict-free 256B-row pattern. NO forced wave cap (r7's (512,4) caused 64-VGPR spill).
__launch_bounds__(512, 1)
__global__ void k_attn(const unsigned short* __restrict__ qs,
                       const unsigned short* __restrict__ kbuf,
                       const unsigned short* __restrict__ vt,
                       const float* __restrict__ mask,
                       unsigned short* __restrict__ ctx) {
  __shared__ unsigned short smem[33280];   // 65KB: 2 x (K 16KB | V 16KB); reuse: o-share 64KB + ML 1KB; obuf 32KB

  int bid0 = blockIdx.x;
  int bid = (bid0 & 7) * 64 + (bid0 >> 3);   // XCD chunked: 8 bh per XCD
  int qc = bid & 7;                          // 8 q-chunks of 128
  int bh = bid >> 3;
  int b = bh >> 2, h = bh & 3;
  int tid = threadIdx.x;
  int w = tid >> 6, l = tid & 63;
  int kvg = w >> 2, wq = w & 3, sw = w & 3;
  int half = l >> 5, lq = l & 31;

  const unsigned short* kbase = kbuf + (size_t)bh * 1024 * 128;
  const unsigned short* vtbase = vt + (size_t)bh * 128 * 1024;
  const float* mbase = mask + b * 1024;

  // Q fragments (B-operand): lane: q = lq, dk = c*16 + half*8 + j
  s16x8 aq[8];
  {
    const unsigned short* qrow = qs + ((size_t)bh * 1024 + qc * 128 + wq * 32 + lq) * 128 + half * 8;
#pragma unroll
    for (int c = 0; c < 8; ++c)
      aq[c] = *reinterpret_cast<const s16x8*>(qrow + c * 16);
  }

  s16x8 bone = {};                        // B[k][q] = 1 at k==0
  bone[0] = (short)(half == 0 ? 0x3F80 : 0);

  f32x16 o[4] = {};                       // O^T tiles, d = dt*32 + rows
  float M = NEGBIG, L = 0.f;

  // active-KV bitmask over 16 tiles of 64 (wave-uniform)
  unsigned amask = 0;
  for (int kb = 0; kb < 16; ++kb) {
    if (__ballot(mbase[kb * 64 + l] != 0.f) != 0ull) amask |= (1u << kb);
  }

  unsigned short* mybuf = smem + kvg * 16384;

  // stage one 64-key tile with a 4-wave group (sw in 0..3)
  auto stage4 = [&](int kb) {
    unsigned short* kd = mybuf;
    unsigned short* vd = mybuf + 8192;
    int rk = l >> 4, ck = l & 15;
#pragma unroll
    for (int it = 0; it < 4; ++it) {
      int r0 = it * 16 + sw * 4;
      int r = r0 + rk;
      int rx = r & 15;
      // K row r: K[kb*64+r][d 0..127]; inverse-swizzled global granule
      gload16(kbase + (size_t)(kb * 64 + r) * 128 + (ck ^ rx) * 8, kd + r0 * 128);
      // V packed row r: logical granule gv -> d = r + (gv>=8)*64, koff = (gv&7)*8
      int gv = ck ^ rx;
      int dv = r + ((gv >> 3) << 6);
      gload16(vtbase + (size_t)dv * 1024 + kb * 64 + (gv & 7) * 8, vd + r0 * 128);
    }
  };

  unsigned rem = amask;
  while (rem) {
    int kba = __ffs(rem) - 1; rem &= rem - 1;
    int kbb = -1;
    if (rem) { kbb = __ffs(rem) - 1; rem &= rem - 1; }
    int mykb = kvg ? kbb : kba;

    __syncthreads();                      // prior tile's readers done
    if (mykb >= 0) stage4(mykb);
    __syncthreads();                      // staged data visible

    if (mykb >= 0) {
      const unsigned short* kl = mybuf;
      const unsigned short* vl = mybuf + 8192;

      // ---- QK^T: 2 tiles of S^T[32k][32q]; bias-MFMA injects -BIG at masked k
      f32x16 s[2];
      __builtin_amdgcn_s_setprio(1);
#pragma unroll
      for (int kt = 0; kt < 2; ++kt) {
        float mv = mbase[mykb * 64 + kt * 32 + lq];
        s16x8 ba = {};
        ba[0] = (short)((half == 0 && mv == 0.f) ? (short)0xFF7F : 0);  // bf16 -3.39e38
        f32x16 z = {};
        s[kt] = __builtin_amdgcn_mfma_f32_32x32x16_bf16(ba, bone, z, 0, 0, 0);
        int row = kt * 32 + lq, rx = row & 15;
#pragma unroll
        for (int c = 0; c < 8; ++c) {
          s16x8 kf = *reinterpret_cast<const s16x8*>(kl + row * 128 + (((c * 2 + half) ^ rx) * 8));
          s[kt] = __builtin_amdgcn_mfma_f32_32x32x16_bf16(kf, aq[c], s[kt], 0, 0, 0);
        }
      }
      __builtin_amdgcn_s_setprio(0);

      // ---- online softmax with defer-max (log2 domain)
      float pmax = fmaxf(vmax16(s[0]), vmax16(s[1]));
      pmax = xchg_max(pmax);
      if (!__all(pmax <= M + 8.f)) {
        float mnew = fmaxf(M, pmax);
        float alpha = exp2f(M - mnew);
        M = mnew;
        L *= alpha;
#pragma unroll
        for (int dt = 0; dt < 4; ++dt)
#pragma unroll
          for (int i = 0; i < 16; ++i) o[dt][i] *= alpha;
      }
      float ls0 = 0.f, ls1 = 0.f, ls2 = 0.f, ls3 = 0.f;
#pragma unroll
      for (int kt = 0; kt < 2; ++kt) {
#pragma unroll
        for (int i = 0; i < 16; ++i) {
          float p = exp2f(s[kt][i] - M);
          s[kt][i] = p;
          if ((i & 3) == 0) ls0 += p; else if ((i & 3) == 1) ls1 += p;
          else if ((i & 3) == 2) ls2 += p; else ls3 += p;
        }
      }
      float ls = (ls0 + ls1) + (ls2 + ls3);
      ls = xchg_sum(ls);
      L += ls;

      // ---- pack P^T (cvt_pk + permlane32_swap) and PV
      __builtin_amdgcn_s_setprio(1);
#pragma unroll
      for (int kt = 0; kt < 2; ++kt) {
        unsigned w0 = cvt_pk_bf16(s[kt][0], s[kt][1]);
        unsigned w1 = cvt_pk_bf16(s[kt][2], s[kt][3]);
        unsigned w2 = cvt_pk_bf16(s[kt][4], s[kt][5]);
        unsigned w3 = cvt_pk_bf16(s[kt][6], s[kt][7]);
        unsigned w4 = cvt_pk_bf16(s[kt][8], s[kt][9]);
        unsigned w5 = cvt_pk_bf16(s[kt][10], s[kt][11]);
        unsigned w6 = cvt_pk_bf16(s[kt][12], s[kt][13]);
        unsigned w7 = cvt_pk_bf16(s[kt][14], s[kt][15]);
        asm("v_permlane32_swap_b32 %0, %1" : "+v"(w0), "+v"(w2));
        asm("v_permlane32_swap_b32 %0, %1" : "+v"(w1), "+v"(w3));
        asm("v_permlane32_swap_b32 %0, %1" : "+v"(w4), "+v"(w6));
        asm("v_permlane32_swap_b32 %0, %1" : "+v"(w5), "+v"(w7));
        u32x4 f0 = {w0, w1, w2, w3};
        u32x4 f1 = {w4, w5, w6, w7};
        s16x8 p0 = __builtin_bit_cast(s16x8, f0);   // k = kt*32 + 0..15
        s16x8 p1 = __builtin_bit_cast(s16x8, f1);   // k = kt*32 + 16..31
#pragma unroll
        for (int dt = 0; dt < 4; ++dt) {
          int lrow = (dt & 1) * 32 + lq;    // packed-V row for d = dt*32+lq
          int h8 = dt >> 1;                 // high-d half selector
          int rx = lrow & 15;
          s16x8 va = *reinterpret_cast<const s16x8*>(vl + lrow * 128 + (((h8 * 8 + kt * 4 + half) ^ rx) * 8));
          o[dt] = __builtin_amdgcn_mfma_f32_32x32x16_bf16(va, p0, o[dt], 0, 0, 0);
          s16x8 vb = *reinterpret_cast<const s16x8*>(vl + lrow * 128 + (((h8 * 8 + kt * 4 + 2 + half) ^ rx) * 8));
          o[dt] = __builtin_amdgcn_mfma_f32_32x32x16_bf16(vb, p1, o[dt], 0, 0, 0);
        }
      }
      __builtin_amdgcn_s_setprio(0);
    }
  }

  // ---- flash merge of the two KV-groups via LDS
  __syncthreads();                        // all compute done, smem free
  float* oshare = reinterpret_cast<float*>(smem);            // [wq][d=128][q=32]
  float* mlf = reinterpret_cast<float*>(smem) + 16384;       // [wq][q=32][2]
  if (kvg == 1) {
#pragma unroll
    for (int dt = 0; dt < 4; ++dt)
#pragma unroll
      for (int i = 0; i < 16; ++i) {
        int rowi = (i & 3) + 8 * (i >> 2) + 4 * half;
        oshare[wq * 4096 + (dt * 32 + rowi) * 32 + lq] = o[dt][i];
      }
    if (half == 0) { mlf[wq * 64 + lq * 2] = M; mlf[wq * 64 + lq * 2 + 1] = L; }
  }
  __syncthreads();
  if (kvg == 0) {
    float M1 = mlf[wq * 64 + lq * 2], L1 = mlf[wq * 64 + lq * 2 + 1];
    float mnew = fmaxf(M, M1);
    float a0 = exp2f(M - mnew), a1 = exp2f(M1 - mnew);
    L = L * a0 + L1 * a1;
#pragma unroll
    for (int dt = 0; dt < 4; ++dt)
#pragma unroll
      for (int i = 0; i < 16; ++i) {
        int rowi = (i & 3) + 8 * (i >> 2) + 4 * half;
        o[dt][i] = o[dt][i] * a0 + oshare[wq * 4096 + (dt * 32 + rowi) * 32 + lq] * a1;
      }
  }
  __syncthreads();

  // ---- epilogue: O^T -> LDS transpose -> coalesced ctx write (g0 holds merged o)
  unsigned short* obuf = smem;            // [128 q][128 d] bf16, 8B-granule XOR (row&15)
  if (kvg == 0) {
    float inv = (L > 0.f) ? 1.0f / L : 0.f;
#pragma unroll
    for (int dt = 0; dt < 4; ++dt) {
#pragma unroll
      for (int g = 0; g < 4; ++g) {
        int d0 = dt * 32 + g * 8 + half * 4;
        unsigned lo = cvt_pk_bf16(o[dt][g * 4 + 0] * inv, o[dt][g * 4 + 1] * inv);
        unsigned hi = cvt_pk_bf16(o[dt][g * 4 + 2] * inv, o[dt][g * 4 + 3] * inv);
        int row = wq * 32 + lq;
        int gr = d0 >> 2;
        uint2 uv; uv.x = lo; uv.y = hi;
        *reinterpret_cast<uint2*>(obuf + row * 128 + ((gr ^ (row & 15)) * 4)) = uv;
      }
    }
  }
  __syncthreads();
  size_t cbase = ((size_t)b * 1024 + qc * 128) * 512 + h * 128;
#pragma unroll
  for (int it = 0; it < 8; ++it) {
    int chunk = it * 512 + tid;
    int row = chunk >> 5, gr = chunk & 31;
    uint2 v = *reinterpret_cast<uint2*>(obuf + row * 128 + ((gr ^ (row & 15)) * 4));
    *reinterpret_cast<uint2*>(ctx + cbase + (size_t)row * 512 + gr * 4) = v;
  }
}

// ---------------------------------------------------------------- launch
extern "C" void kernel_launch(void* const* d_in, const int* in_sizes, int n_in,
                              void* d_out, int out_size, void* d_ws, size_t ws_size,
                              hipStream_t stream) {
  const float* x      = (const float*)d_in[0];
  const float* mask   = (const float*)d_in[1];
  const float* w_qkv  = (const float*)d_in[2];
  const float* b_qkv  = (const float*)d_in[3];
  const float* w_out  = (const float*)d_in[4];
  const float* b_out  = (const float*)d_in[5];
  const float* w_fsmn = (const float*)d_in[6];
  float* out = (float*)d_out;

  char* ws = (char*)d_ws;
  size_t off = 0;
  auto alloc = [&](size_t bytes) { void* p = ws + off; off += (bytes + 255) & ~(size_t)255; return p; };
  unsigned short* x_bf   = (unsigned short*)alloc(16384ull * 512 * 2);
  unsigned short* wT_qkv = (unsigned short*)alloc(1536ull * 512 * 2);
  unsigned short* wT_out = (unsigned short*)alloc(512ull * 512 * 2);
  unsigned short* qs     = (unsigned short*)alloc(64ull * 1024 * 128 * 2);
  unsigned short* kbuf   = (unsigned short*)alloc(64ull * 1024 * 128 * 2);
  unsigned short* vt     = (unsigned short*)alloc(64ull * 128 * 1024 * 2);
  unsigned short* vbf    = (unsigned short*)alloc(16384ull * 512 * 2);
  unsigned short* ctx    = (unsigned short*)alloc(16384ull * 512 * 2);

  k_prep<<<4608, 256, 0, stream>>>(x, x_bf, w_qkv, wT_qkv, w_out, wT_out);
  k_gemm<0><<<128 * 12, 256, 0, stream>>>(x_bf, wT_qkv, b_qkv, mask, nullptr, nullptr,
                                          qs, kbuf, vbf, vt, nullptr, 12, (128 * 12) / 8);
  k_attn<<<512, 512, 0, stream>>>(qs, kbuf, vt, mask, ctx);
  k_gemm<1><<<128 * 4, 256, 0, stream>>>(ctx, wT_out, b_out, mask, w_fsmn, vbf,
                                         nullptr, nullptr, nullptr, nullptr, out, 4, (128 * 4) / 8);
}

// Round 9
// 201.079 us; speedup vs baseline: 1.6001x; 1.0675x over previous
//
#include <hip/hip_runtime.h>
#include <stdint.h>

// Problem constants (B=16, T=1024, F=512, H=4, dk=128, kernel=11, pad 5/5)
#define SCALE_Q 0.08838834764831845f   // 1/sqrt(128)
#define LOG2E 1.4426950408889634f
#define NEGBIG -1e30f

typedef __attribute__((ext_vector_type(4))) float f32x4;
typedef __attribute__((ext_vector_type(16))) float f32x16;
typedef __attribute__((ext_vector_type(8))) short s16x8;
typedef __attribute__((ext_vector_type(4))) unsigned u32x4;

static __device__ __forceinline__ unsigned short f2bf(float f) {
  unsigned int u = __builtin_bit_cast(unsigned int, f);
  u += 0x7FFFu + ((u >> 16) & 1u);           // round-to-nearest-even
  return (unsigned short)(u >> 16);
}
static __device__ __forceinline__ float bf2f(unsigned short b) {
  unsigned int u = ((unsigned int)b) << 16;
  return __builtin_bit_cast(float, u);
}

static __device__ __forceinline__ unsigned cvt_pk_bf16(float lo, float hi) {
  unsigned r;
  asm("v_cvt_pk_bf16_f32 %0, %1, %2" : "=v"(r) : "v"(lo), "v"(hi));
  return r;
}

static __device__ __forceinline__ float xchg_max(float x) {
  float a = x, b = x;
  asm("v_permlane32_swap_b32 %0, %1" : "+v"(a), "+v"(b));
  return fmaxf(a, b);
}
static __device__ __forceinline__ float xchg_sum(float x) {
  float a = x, b = x;
  asm("v_permlane32_swap_b32 %0, %1" : "+v"(a), "+v"(b));
  return a + b;
}

// max3-friendly 16-way max (clang fuses fmaxf(fmaxf(a,b),c) -> v_max3_f32)
static __device__ __forceinline__ float vmax16(const f32x16& v) {
  float m0 = fmaxf(fmaxf(v[0], v[1]), v[2]);
  float m1 = fmaxf(fmaxf(v[3], v[4]), v[5]);
  float m2 = fmaxf(fmaxf(v[6], v[7]), v[8]);
  float m3 = fmaxf(fmaxf(v[9], v[10]), v[11]);
  float m4 = fmaxf(fmaxf(v[12], v[13]), v[14]);
  float m5 = fmaxf(fmaxf(v[15], m0), m1);
  return fmaxf(fmaxf(fmaxf(m2, m3), m4), m5);
}

// async global->LDS, 16B per lane. LDS dest must be wave-uniform base (+lane*16 implicit).
static __device__ __forceinline__ void gload16(const void* g, void* l) {
  __builtin_amdgcn_global_load_lds(
      (const __attribute__((address_space(1))) void*)g,
      (__attribute__((address_space(3))) void*)l, 16, 0, 0);
}

// ---------------------------------------------------------------- prep (fused convert + transposes)
__global__ void k_prep(const float* __restrict__ x, unsigned short* __restrict__ xb,
                       const float* __restrict__ w_qkv, unsigned short* __restrict__ wtq,
                       const float* __restrict__ w_out, unsigned short* __restrict__ wto) {
  int bid = blockIdx.x;
  int tid = threadIdx.x;
  if (bid < 4096) {
    int i = (bid * 256 + tid) * 8;
    const float4* p = reinterpret_cast<const float4*>(x + i);
    float4 a = p[0], b = p[1];
    s16x8 o;
    o[0] = f2bf(a.x); o[1] = f2bf(a.y); o[2] = f2bf(a.z); o[3] = f2bf(a.w);
    o[4] = f2bf(b.x); o[5] = f2bf(b.y); o[6] = f2bf(b.z); o[7] = f2bf(b.w);
    *reinterpret_cast<s16x8*>(xb + i) = o;
  } else if (bid < 4096 + 384) {
    int gid = (bid - 4096) * 256 + tid;
    int n = gid >> 6, k0 = (gid & 63) * 8;
    s16x8 o;
#pragma unroll
    for (int j = 0; j < 8; ++j) o[j] = f2bf(w_qkv[(size_t)(k0 + j) * 1536 + n]);
    *reinterpret_cast<s16x8*>(wtq + (size_t)n * 512 + k0) = o;
  } else {
    int gid = (bid - 4480) * 256 + tid;
    int n = gid >> 6, k0 = (gid & 63) * 8;
    s16x8 o;
#pragma unroll
    for (int j = 0; j < 8; ++j) o[j] = f2bf(w_out[(size_t)(k0 + j) * 512 + n]);
    *reinterpret_cast<s16x8*>(wto + (size_t)n * 512 + k0) = o;
  }
}

// ---------------------------------------------------------------- GEMM core
// A [M][512] bf16, Bt [N][512] bf16. 128x128 tile, BK=64, 4 waves (2x2), 16x16x32 MFMA.
// Double-buffered global_load_lds, prefetch-under-compute, rb-major L2 mapping.
// MODE 0: qkv epilogue (scatter q,k,v_bf16,vT) + masked-row tile skip.
// MODE 1: out epilogue (+bias + FUSED FSMN depthwise conv + residual -> fp32).
template <int MODE>
__launch_bounds__(256, 2)
__global__ void k_gemm(const unsigned short* __restrict__ A,
                       const unsigned short* __restrict__ Bt,
                       const float* __restrict__ bias,
                       const float* __restrict__ mask,
                       const float* __restrict__ wf,      // w_fsmn (MODE 1)
                       const unsigned short* __restrict__ vsrc, // v bf16 [b,t,d] (MODE 1)
                       unsigned short* __restrict__ qs, unsigned short* __restrict__ kbuf,
                       unsigned short* __restrict__ vbf, unsigned short* __restrict__ vt,
                       float* __restrict__ outp,
                       int tiles_n, int cpx) {
  __shared__ unsigned short smem[32768];     // 64KB: 2 bufs x (A 16KB | B 16KB)
  int bid0 = blockIdx.x;
  int bid = (bid0 & 7) * cpx + (bid0 >> 3);  // XCD swizzle (grid % 8 == 0)
  int rb = bid / tiles_n, cb = bid % tiles_n;
  int tid = threadIdx.x;
  int w = tid >> 6, lane = tid & 63;
  int g = lane >> 4, ln = lane & 15;
  int wr = w >> 1, wc = w & 1;

  if constexpr (MODE == 0) {
    if (cb >= 4) {
      int b = (rb * 128) >> 10, t0 = (rb * 128) & 1023;
      const float* mb = mask + b * 1024 + t0;
      float a0 = mb[lane * 2], a1 = mb[lane * 2 + 1];
      if (__ballot(a0 != 0.f || a1 != 0.f) == 0ull) return;
    }
  }

  int sr = lane >> 3;        // row within wave chunk (8 rows/wave/round)
  int sc = lane & 7;         // 16B-granule slot (8 per 128B row)

  auto stage = [&](int kb0, int bsel) {
    unsigned short* al = smem + bsel * 16384;
    unsigned short* bl = al + 8192;
#pragma unroll
    for (int it = 0; it < 4; ++it) {
      int r0 = it * 32 + w * 8;                // wave-uniform row base
      int r = r0 + sr;
      int cg = sc ^ (r & 7);                   // pre-swizzled global granule
      gload16(A + (size_t)(rb * 128 + r) * 512 + kb0 + cg * 8, al + r0 * 64);
      gload16(Bt + (size_t)(cb * 128 + r) * 512 + kb0 + cg * 8, bl + r0 * 64);
    }
  };

  f32x4 acc[4][4] = {};

  stage(0, 0);
  __syncthreads();
  int cur = 0;
  for (int kt = 0; kt < 8; ++kt) {
    if (kt < 7) stage((kt + 1) * 64, cur ^ 1); // flies under compute
    const unsigned short* al = smem + cur * 16384;
    const unsigned short* bl = al + 8192;
#pragma unroll
    for (int kk = 0; kk < 2; ++kk) {
      s16x8 af[4], bf[4];
#pragma unroll
      for (int m = 0; m < 4; ++m) {
        int row = wr * 64 + m * 16 + ln;
        af[m] = *reinterpret_cast<const s16x8*>(al + row * 64 + (((kk * 4 + g) ^ (row & 7)) * 8));
      }
#pragma unroll
      for (int n = 0; n < 4; ++n) {
        int row = wc * 64 + n * 16 + ln;
        bf[n] = *reinterpret_cast<const s16x8*>(bl + row * 64 + (((kk * 4 + g) ^ (row & 7)) * 8));
      }
#pragma unroll
      for (int m = 0; m < 4; ++m)
#pragma unroll
        for (int n = 0; n < 4; ++n)
          acc[m][n] = __builtin_amdgcn_mfma_f32_16x16x32_bf16(af[m], bf[n], acc[m][n], 0, 0, 0);
    }
    __syncthreads();
    cur ^= 1;
  }

  int c0 = cb * 128;
  int R0 = rb * 128 + wr * 64;

  if constexpr (MODE == 0) {
#pragma unroll
    for (int m = 0; m < 4; ++m) {
#pragma unroll
      for (int n = 0; n < 4; ++n) {
        int col = c0 + wc * 64 + n * 16 + ln;
        int Rbase = R0 + m * 16 + g * 4;
        float bv = bias[col];
        int which = col >> 9;          // 0=q 1=k 2=v  (uniform per block)
        int h = (col >> 7) & 3;        // uniform per block
        int d = col & 127;
        int b = Rbase >> 10, t0 = Rbase & 1023;
        if (which == 2) {
          unsigned short pk[4];
#pragma unroll
          for (int r = 0; r < 4; ++r) {
            float v = acc[m][n][r] + bv;
            pk[r] = f2bf(v);
            vbf[(size_t)(Rbase + r) * 512 + (col - 1024)] = pk[r];
          }
          uint2 uv;
          uv.x = (unsigned)pk[0] | ((unsigned)pk[1] << 16);
          uv.y = (unsigned)pk[2] | ((unsigned)pk[3] << 16);
          *reinterpret_cast<uint2*>(vt + ((size_t)((b * 4 + h) * 128 + d)) * 1024 + t0) = uv;
        } else {
          unsigned short* dst = (which == 0) ? qs : kbuf;
          float sc2 = (which == 0) ? (SCALE_Q * LOG2E) : 1.0f;   // fold log2e for exp2 softmax
#pragma unroll
          for (int r = 0; r < 4; ++r) {
            int t = t0 + r;
            dst[((size_t)((b * 4 + h) * 1024 + t)) * 128 + d] = f2bf((acc[m][n][r] + bv) * sc2);
          }
        }
      }
    }
  } else {
    // fused FSMN epilogue
    int b = (rb * 128) >> 10, tloc0 = (rb * 128) & 1023;
    unsigned short* vh = smem;                          // 138*136 u16
    float* wl = reinterpret_cast<float*>(smem + 18816); // 128*11 f32
    for (int idx = tid; idx < 138 * 16; idx += 256) {
      int i = idx >> 4, gc = idx & 15;
      int tl = tloc0 - 5 + i;
      s16x8 v8 = {};
      if (tl >= 0 && tl < 1024) {
        if (mask[b * 1024 + tl] != 0.f)
          v8 = *reinterpret_cast<const s16x8*>(vsrc + ((size_t)b * 1024 + tl) * 512 + c0 + gc * 8);
      }
      *reinterpret_cast<s16x8*>(vh + i * 136 + gc * 8) = v8;
    }
    if (tid < 128) {
#pragma unroll
      for (int j = 0; j < 11; ++j) wl[tid * 11 + j] = wf[(c0 + tid) * 11 + j];
    }
    __syncthreads();

#pragma unroll
    for (int m = 0; m < 4; ++m) {
      int Rbase = R0 + m * 16 + g * 4;
      int lrb = Rbase - rb * 128;
      float mk[4];
#pragma unroll
      for (int r = 0; r < 4; ++r) mk[r] = mask[b * 1024 + ((Rbase + r) & 1023)];
#pragma unroll
      for (int n = 0; n < 4; ++n) {
        int lc = wc * 64 + n * 16 + ln;
        int col = c0 + lc;
        float bv = bias[col];
        float win[14];
#pragma unroll
        for (int i = 0; i < 14; ++i) win[i] = bf2f(vh[(lrb + i) * 136 + lc]);
        float wj[11];
#pragma unroll
        for (int j = 0; j < 11; ++j) wj[j] = wl[lc * 11 + j];
#pragma unroll
        for (int r = 0; r < 4; ++r) {
          float conv = win[r + 5];         // residual
#pragma unroll
          for (int j = 0; j < 11; ++j) conv += wj[j] * win[r + j];
          size_t idx = (size_t)(Rbase + r) * 512 + col;
          outp[idx] = acc[m][n][r] + bv + conv * mk[r];
        }
      }
    }
  }
}

// ---------------------------------------------------------------- flash attention (round-5 structure + defer-max)
// Swapped-QK^T, in-register softmax, double-buffered K/V via global_load_lds with
// prefetch-under-compute (1 barrier per tile). 8 waves x 32 q = 256 q/block, KVBLK=128.
__launch_bounds__(512, 1)
__global__ void k_attn(const unsigned short* __restrict__ qs,
                       const unsigned short* __restrict__ kbuf,
                       const unsigned short* __restrict__ vt,
                       const float* __restrict__ mask,
                       unsigned short* __restrict__ ctx) {
  __shared__ unsigned short smem[2 * 32768];   // 128KB: buf{0,1} x {K 128x128 | V^T 128x128}

  int bid0 = blockIdx.x;
  int bid = (bid0 & 7) * 32 + (bid0 >> 3);     // XCD swizzle (256 blocks, 8 XCDs)
  int qc = bid & 3;
  int bh = bid >> 2;
  int b = bh >> 2, h = bh & 3;
  int tid = threadIdx.x;
  int w = tid >> 6, l = tid & 63;
  int half = l >> 5, lq = l & 31;

  const unsigned short* kbase = kbuf + (size_t)bh * 1024 * 128;
  const unsigned short* vtbase = vt + (size_t)bh * 128 * 1024;
  const float* mbase = mask + b * 1024;

  // Q fragments (B-operand): lane: q = lq, dk = c*16 + half*8 + j
  s16x8 aq[8];
  {
    const unsigned short* qrow = qs + ((size_t)bh * 1024 + qc * 256 + w * 32 + lq) * 128 + half * 8;
#pragma unroll
    for (int c = 0; c < 8; ++c)
      aq[c] = *reinterpret_cast<const s16x8*>(qrow + c * 16);
  }

  s16x8 bone = {};                        // B[k][q] = 1 at k==0
  bone[0] = (short)(half == 0 ? 0x3F80 : 0);

  f32x16 o[4] = {};                       // O^T tiles, d = dt*32 + rows
  float M = NEGBIG, L = 0.f;

  // active-KV bitmask (wave-uniform, same in all waves)
  unsigned amask = 0;
  for (int kb = 0; kb < 8; ++kb) {
    float m0 = mbase[kb * 128 + l];
    float m1 = mbase[kb * 128 + 64 + l];
    if (__ballot((m0 != 0.f) || (m1 != 0.f)) != 0ull) amask |= (1u << kb);
  }

  // stage one KV tile into buffer bsel (8 x global_load_lds per wave)
  auto stage = [&](int kb, int bsel) {
    unsigned short* kd = smem + bsel * 32768;
    unsigned short* vd = kd + 16384;
    int srl = l >> 4;                     // 4 rows per wave per round
    int scl = l & 15;
#pragma unroll
    for (int it = 0; it < 4; ++it) {
      int r0 = it * 32 + w * 4;           // wave-uniform row base
      int r = r0 + srl;
      int cg = scl ^ (r & 15);            // pre-swizzled global granule
      gload16(kbase + (size_t)(kb * 128 + r) * 128 + cg * 8, kd + r0 * 128);
      gload16(vtbase + (size_t)r * 1024 + kb * 128 + cg * 8, vd + r0 * 128);
    }
  };

  unsigned rem = amask;
  int kb_cur = __ffs(rem) - 1; rem &= rem - 1;
  stage(kb_cur, 0);
  __syncthreads();                        // buf0 ready
  int cur = 0;

  while (true) {
    int kb_next = rem ? (__ffs(rem) - 1) : -1;
    if (kb_next >= 0) { rem &= rem - 1; stage(kb_next, cur ^ 1); }  // flies under compute

    unsigned short* kl = smem + cur * 32768;
    unsigned short* vl = kl + 16384;

    // ---- QK^T: 4 tiles of S^T[32k][32q]; bias-MFMA injects -BIG at masked k
    f32x16 s[4];
    __builtin_amdgcn_s_setprio(1);
#pragma unroll
    for (int kt = 0; kt < 4; ++kt) {
      float mv = mbase[kb_cur * 128 + kt * 32 + lq];
      s16x8 ba = {};
      ba[0] = (short)((half == 0 && mv == 0.f) ? (short)0xFF7F : 0);  // bf16 -3.39e38
      f32x16 z = {};
      s[kt] = __builtin_amdgcn_mfma_f32_32x32x16_bf16(ba, bone, z, 0, 0, 0);
      int row = kt * 32 + lq, rx = row & 15;
#pragma unroll
      for (int c = 0; c < 8; ++c) {
        s16x8 kf = *reinterpret_cast<const s16x8*>(kl + row * 128 + (((c * 2 + half) ^ rx) * 8));
        s[kt] = __builtin_amdgcn_mfma_f32_32x32x16_bf16(kf, aq[c], s[kt], 0, 0, 0);
      }
    }
    __builtin_amdgcn_s_setprio(0);

    // ---- online softmax with defer-max (log2 domain; per-lane scalar M/L for q = lq)
    float mx = fmaxf(fmaxf(vmax16(s[0]), vmax16(s[1])), fmaxf(vmax16(s[2]), vmax16(s[3])));
    mx = xchg_max(mx);
    if (!__all(mx <= M + 8.f)) {
      float mnew = fmaxf(M, mx);
      float alpha = exp2f(M - mnew);
      M = mnew;
      L *= alpha;
#pragma unroll
      for (int dt = 0; dt < 4; ++dt)
#pragma unroll
        for (int i = 0; i < 16; ++i) o[dt][i] *= alpha;
    }
    float ls0 = 0.f, ls1 = 0.f, ls2 = 0.f, ls3 = 0.f;
#pragma unroll
    for (int kt = 0; kt < 4; ++kt) {
#pragma unroll
      for (int i = 0; i < 16; ++i) {
        float p = exp2f(s[kt][i] - M);
        s[kt][i] = p;
        if ((i & 3) == 0) ls0 += p; else if ((i & 3) == 1) ls1 += p;
        else if ((i & 3) == 2) ls2 += p; else ls3 += p;
      }
    }
    float ls = (ls0 + ls1) + (ls2 + ls3);
    ls = xchg_sum(ls);
    L += ls;

    // ---- pack P^T into B-frags (cvt_pk + permlane32_swap), PV per kt
    __builtin_amdgcn_s_setprio(1);
#pragma unroll
    for (int kt = 0; kt < 4; ++kt) {
      unsigned w0 = cvt_pk_bf16(s[kt][0], s[kt][1]);
      unsigned w1 = cvt_pk_bf16(s[kt][2], s[kt][3]);
      unsigned w2 = cvt_pk_bf16(s[kt][4], s[kt][5]);
      unsigned w3 = cvt_pk_bf16(s[kt][6], s[kt][7]);
      unsigned w4 = cvt_pk_bf16(s[kt][8], s[kt][9]);
      unsigned w5 = cvt_pk_bf16(s[kt][10], s[kt][11]);
      unsigned w6 = cvt_pk_bf16(s[kt][12], s[kt][13]);
      unsigned w7 = cvt_pk_bf16(s[kt][14], s[kt][15]);
      asm("v_permlane32_swap_b32 %0, %1" : "+v"(w0), "+v"(w2));
      asm("v_permlane32_swap_b32 %0, %1" : "+v"(w1), "+v"(w3));
      asm("v_permlane32_swap_b32 %0, %1" : "+v"(w4), "+v"(w6));
      asm("v_permlane32_swap_b32 %0, %1" : "+v"(w5), "+v"(w7));
      u32x4 f0 = {w0, w1, w2, w3};
      u32x4 f1 = {w4, w5, w6, w7};
      s16x8 p0 = __builtin_bit_cast(s16x8, f0);   // k = kt*32 + 0..15
      s16x8 p1 = __builtin_bit_cast(s16x8, f1);   // k = kt*32 + 16..31
#pragma unroll
      for (int dt = 0; dt < 4; ++dt) {
        int row = dt * 32 + lq, rx = row & 15;
        s16x8 va = *reinterpret_cast<const s16x8*>(vl + row * 128 + (((kt * 4 + half) ^ rx) * 8));
        o[dt] = __builtin_amdgcn_mfma_f32_32x32x16_bf16(va, p0, o[dt], 0, 0, 0);
        s16x8 vb = *reinterpret_cast<const s16x8*>(vl + row * 128 + (((kt * 4 + 2 + half) ^ rx) * 8));
        o[dt] = __builtin_amdgcn_mfma_f32_32x32x16_bf16(vb, p1, o[dt], 0, 0, 0);
      }
    }
    __builtin_amdgcn_s_setprio(0);

    if (kb_next < 0) break;
    __syncthreads();                      // next buf staged; readers of cur done
    kb_cur = kb_next; cur ^= 1;
  }

  // ---- epilogue: O^T -> LDS transpose -> coalesced ctx write
  float inv = 1.0f / L;
  __syncthreads();
  unsigned short* obuf = smem;            // [256 q][128 d] bf16, 8B-granule XOR (row&15)
#pragma unroll
  for (int dt = 0; dt < 4; ++dt) {
#pragma unroll
    for (int g = 0; g < 4; ++g) {
      int d0 = dt * 32 + g * 8 + half * 4;
      unsigned lo = cvt_pk_bf16(o[dt][g * 4 + 0] * inv, o[dt][g * 4 + 1] * inv);
      unsigned hi = cvt_pk_bf16(o[dt][g * 4 + 2] * inv, o[dt][g * 4 + 3] * inv);
      int row = w * 32 + lq;
      int gr = d0 >> 2;
      uint2 uv; uv.x = lo; uv.y = hi;
      *reinterpret_cast<uint2*>(obuf + row * 128 + ((gr ^ (row & 15)) * 4)) = uv;
    }
  }
  __syncthreads();
  size_t cbase = ((size_t)b * 1024 + qc * 256) * 512 + h * 128;
#pragma unroll
  for (int it = 0; it < 16; ++it) {
    int chunk = it * 512 + tid;
    int row = chunk >> 5, gr = chunk & 31;
    uint2 v = *reinterpret_cast<uint2*>(obuf + row * 128 + ((gr ^ (row & 15)) * 4));
    *reinterpret_cast<uint2*>(ctx + cbase + (size_t)row * 512 + gr * 4) = v;
  }
}

// ---------------------------------------------------------------- launch
extern "C" void kernel_launch(void* const* d_in, const int* in_sizes, int n_in,
                              void* d_out, int out_size, void* d_ws, size_t ws_size,
                              hipStream_t stream) {
  const float* x      = (const float*)d_in[0];
  const float* mask   = (const float*)d_in[1];
  const float* w_qkv  = (const float*)d_in[2];
  const float* b_qkv  = (const float*)d_in[3];
  const float* w_out  = (const float*)d_in[4];
  const float* b_out  = (const float*)d_in[5];
  const float* w_fsmn = (const float*)d_in[6];
  float* out = (float*)d_out;

  char* ws = (char*)d_ws;
  size_t off = 0;
  auto alloc = [&](size_t bytes) { void* p = ws + off; off += (bytes + 255) & ~(size_t)255; return p; };
  unsigned short* x_bf   = (unsigned short*)alloc(16384ull * 512 * 2);
  unsigned short* wT_qkv = (unsigned short*)alloc(1536ull * 512 * 2);
  unsigned short* wT_out = (unsigned short*)alloc(512ull * 512 * 2);
  unsigned short* qs     = (unsigned short*)alloc(64ull * 1024 * 128 * 2);
  unsigned short* kbuf   = (unsigned short*)alloc(64ull * 1024 * 128 * 2);
  unsigned short* vt     = (unsigned short*)alloc(64ull * 128 * 1024 * 2);
  unsigned short* vbf    = (unsigned short*)alloc(16384ull * 512 * 2);
  unsigned short* ctx    = (unsigned short*)alloc(16384ull * 512 * 2);

  k_prep<<<4608, 256, 0, stream>>>(x, x_bf, w_qkv, wT_qkv, w_out, wT_out);
  k_gemm<0><<<128 * 12, 256, 0, stream>>>(x_bf, wT_qkv, b_qkv, mask, nullptr, nullptr,
                                          qs, kbuf, vbf, vt, nullptr, 12, (128 * 12) / 8);
  k_attn<<<256, 512, 0, stream>>>(qs, kbuf, vt, mask, ctx);
  k_gemm<1><<<128 * 4, 256, 0, stream>>>(ctx, wT_out, b_out, mask, w_fsmn, vbf,
                                         nullptr, nullptr, nullptr, nullptr, out, 4, (128 * 4) / 8);
}